// Round 3
// baseline (479.080 us; speedup 1.0000x reference)
//
#include <hip/hip_runtime.h>
#include <hip/hip_bf16.h>

#define NB    32      // batch
#define NCAP  2048    // input capsules
#define CL    1024    // C*L
#define ILEN  32

__device__ inline unsigned int pack2_bf16(float lo, float hi) {
    unsigned int a = __float_as_uint(lo);
    a += 0x7FFFu + ((a >> 16) & 1u);
    unsigned int b = __float_as_uint(hi);
    b += 0x7FFFu + ((b >> 16) & 1u);
    return (a >> 16) | (b & 0xFFFF0000u);
}

__device__ inline void unpack8(uint4 a, float* f) {
    f[0] = __uint_as_float(a.x << 16);
    f[1] = __uint_as_float(a.x & 0xFFFF0000u);
    f[2] = __uint_as_float(a.y << 16);
    f[3] = __uint_as_float(a.y & 0xFFFF0000u);
    f[4] = __uint_as_float(a.z << 16);
    f[5] = __uint_as_float(a.z & 0xFFFF0000u);
    f[6] = __uint_as_float(a.w << 16);
    f[7] = __uint_as_float(a.w & 0xFFFF0000u);
}

// ---------------------------------------------------------------------------
// Kernel A: u[b,j,k] = sum_i x[b,j,i] * W[j,i,k], stored bf16.
// Block = (j, k-half). W read global->VGPR (L1/L2 serve the 4-wave reuse);
// LDS holds only the transposed 4 KB x tile, read via wave-uniform broadcast
// b128s. Lane owns 8 consecutive k for 8 b -> 16 B coalesced stores.
// ---------------------------------------------------------------------------
__global__ __launch_bounds__(256) void compute_u(const float* __restrict__ x,
                                                 const float* __restrict__ W,
                                                 unsigned short* __restrict__ u) {
    const int j    = blockIdx.x >> 1;
    const int kh   = blockIdx.x & 1;
    const int t    = threadIdx.x;
    const int wv   = t >> 6;    // b-octet
    const int lane = t & 63;    // k-octet (8 consecutive k)

    __shared__ float xs[32][32];   // [i][b] transposed; broadcast reads -> no pad

    {   // conflict-free transposed staging: lane -> b = t&31, i4 = (t>>5)*4
        int b  = t & 31;
        int i4 = (t >> 5) << 2;
        float4 v = *(const float4*)(x + ((size_t)b * NCAP + j) * ILEN + i4);
        xs[i4 + 0][b] = v.x;
        xs[i4 + 1][b] = v.y;
        xs[i4 + 2][b] = v.z;
        xs[i4 + 3][b] = v.w;
    }
    __syncthreads();

    const float* Wb = W + (size_t)j * (ILEN * CL) + kh * 512 + lane * 8;

    float acc[8][8];   // [bb][kk]
#pragma unroll
    for (int bb = 0; bb < 8; ++bb)
#pragma unroll
        for (int kk = 0; kk < 8; ++kk) acc[bb][kk] = 0.f;

#pragma unroll 4
    for (int i = 0; i < 32; ++i) {
        float4 w0 = *(const float4*)(Wb + (size_t)i * CL);
        float4 w1 = *(const float4*)(Wb + (size_t)i * CL + 4);
        float4 x0 = *(const float4*)(&xs[i][wv * 8]);       // broadcast
        float4 x1 = *(const float4*)(&xs[i][wv * 8 + 4]);   // broadcast
        float wk[8] = {w0.x, w0.y, w0.z, w0.w, w1.x, w1.y, w1.z, w1.w};
        float xv[8] = {x0.x, x0.y, x0.z, x0.w, x1.x, x1.y, x1.z, x1.w};
#pragma unroll
        for (int bb = 0; bb < 8; ++bb)
#pragma unroll
            for (int kk = 0; kk < 8; ++kk)
                acc[bb][kk] += xv[bb] * wk[kk];
    }

    const int k = kh * 512 + lane * 8;
#pragma unroll
    for (int bb = 0; bb < 8; ++bb) {
        int b = wv * 8 + bb;
        uint4 o;
        o.x = pack2_bf16(acc[bb][0], acc[bb][1]);
        o.y = pack2_bf16(acc[bb][2], acc[bb][3]);
        o.z = pack2_bf16(acc[bb][4], acc[bb][5]);
        o.w = pack2_bf16(acc[bb][6], acc[bb][7]);
        *(uint4*)(u + ((size_t)b * NCAP + j) * CL + k) = o;
    }
}

// ---------------------------------------------------------------------------
// Routing pass, barrier-free inner loop, 2 j's per iteration (independent
// softmax shfl chains interleave for ILP), depth-4-j prefetch.
// Lane owns capsules c0=lane>>2 and c0+16, 8 l's each.
// ---------------------------------------------------------------------------
template<bool HAS_V>
__global__ __launch_bounds__(256) void route_pass(const unsigned short* __restrict__ u,
                                                  const float* __restrict__ vlog,
                                                  float* __restrict__ spart) {
    const int b    = blockIdx.x;
    const int jc   = blockIdx.y;
    const int t    = threadIdx.x;
    const int wv   = t >> 6;
    const int lane = t & 63;
    const int c0   = lane >> 2;
    const int sub  = lane & 3;
    const int e0   = c0 * 32 + sub * 8;   // fragment 0; fragment 1 at e0+512

    float vme0[8], vme1[8];
    if (HAS_V) {
        const float* vb = vlog + b * CL;
        *(float4*)(vme0)     = *(const float4*)(vb + e0);
        *(float4*)(vme0 + 4) = *(const float4*)(vb + e0 + 4);
        *(float4*)(vme1)     = *(const float4*)(vb + e0 + 512);
        *(float4*)(vme1 + 4) = *(const float4*)(vb + e0 + 516);
    }

    const int jbase = jc * 128 + wv * 32;
    const unsigned short* up = u + ((size_t)b * NCAP + jbase) * CL + e0;

    float acc0[8], acc1[8];
#pragma unroll
    for (int e = 0; e < 8; ++e) { acc0[e] = 0.f; acc1[e] = 0.f; }

    // pipeline: current pair (ca*), next pair (pa*)
    uint4 ca0 = *(const uint4*)(up + 0 * CL);
    uint4 cg0 = *(const uint4*)(up + 0 * CL + 512);
    uint4 ca1 = *(const uint4*)(up + 1 * CL);
    uint4 cg1 = *(const uint4*)(up + 1 * CL + 512);
    uint4 pa0 = *(const uint4*)(up + 2 * CL);
    uint4 pg0 = *(const uint4*)(up + 2 * CL + 512);
    uint4 pa1 = *(const uint4*)(up + 3 * CL);
    uint4 pg1 = *(const uint4*)(up + 3 * CL + 512);

    for (int jj = 0; jj < 32; jj += 2) {
        const int j4 = (jj + 4 < 32) ? jj + 4 : 31;
        const int j5 = (jj + 5 < 32) ? jj + 5 : 31;
        uint4 na0 = *(const uint4*)(up + (size_t)j4 * CL);
        uint4 ng0 = *(const uint4*)(up + (size_t)j4 * CL + 512);
        uint4 na1 = *(const uint4*)(up + (size_t)j5 * CL);
        uint4 ng1 = *(const uint4*)(up + (size_t)j5 * CL + 512);

        float uf0[8], uf1[8], uf2[8], uf3[8];
        unpack8(ca0, uf0); unpack8(cg0, uf1);
        unpack8(ca1, uf2); unpack8(cg1, uf3);

        float cw0, cw1, cw2, cw3;
        if (HAS_V) {
            float p0 = 0.f, p1 = 0.f, p2 = 0.f, p3 = 0.f;
#pragma unroll
            for (int e = 0; e < 8; ++e) {
                p0 += uf0[e] * vme0[e];
                p1 += uf1[e] * vme1[e];
                p2 += uf2[e] * vme0[e];
                p3 += uf3[e] * vme1[e];
            }
            p0 += __shfl_xor(p0, 1); p0 += __shfl_xor(p0, 2);
            p1 += __shfl_xor(p1, 1); p1 += __shfl_xor(p1, 2);
            p2 += __shfl_xor(p2, 1); p2 += __shfl_xor(p2, 2);
            p3 += __shfl_xor(p3, 1); p3 += __shfl_xor(p3, 2);
            float m0 = fmaxf(p0, p1);
            float m1 = fmaxf(p2, p3);
            m0 = fmaxf(m0, __shfl_xor(m0, 4));
            m1 = fmaxf(m1, __shfl_xor(m1, 4));
            m0 = fmaxf(m0, __shfl_xor(m0, 8));
            m1 = fmaxf(m1, __shfl_xor(m1, 8));
            m0 = fmaxf(m0, __shfl_xor(m0, 16));
            m1 = fmaxf(m1, __shfl_xor(m1, 16));
            m0 = fmaxf(m0, __shfl_xor(m0, 32));
            m1 = fmaxf(m1, __shfl_xor(m1, 32));
            float e00 = __expf(p0 - m0), e01 = __expf(p1 - m0);
            float e10 = __expf(p2 - m1), e11 = __expf(p3 - m1);
            float s0 = e00 + e01, s1 = e10 + e11;
            s0 += __shfl_xor(s0, 4);
            s1 += __shfl_xor(s1, 4);
            s0 += __shfl_xor(s0, 8);
            s1 += __shfl_xor(s1, 8);
            s0 += __shfl_xor(s0, 16);
            s1 += __shfl_xor(s1, 16);
            s0 += __shfl_xor(s0, 32);
            s1 += __shfl_xor(s1, 32);
            float i0 = __builtin_amdgcn_rcpf(s0);
            float i1 = __builtin_amdgcn_rcpf(s1);
            cw0 = e00 * i0; cw1 = e01 * i0;
            cw2 = e10 * i1; cw3 = e11 * i1;
        } else {
            cw0 = cw1 = cw2 = cw3 = 0.03125f;
        }
#pragma unroll
        for (int e = 0; e < 8; ++e) {
            acc0[e] += cw0 * uf0[e] + cw2 * uf2[e];
            acc1[e] += cw1 * uf1[e] + cw3 * uf3[e];
        }
        ca0 = pa0; cg0 = pg0; ca1 = pa1; cg1 = pg1;
        pa0 = na0; pg0 = ng0; pa1 = na1; pg1 = ng1;
    }

    // block reduction (no atomics)
    __shared__ float red[4][1024];
    *(float4*)(&red[wv][e0])       = *(float4*)(acc0);
    *(float4*)(&red[wv][e0 + 4])   = *(float4*)(acc0 + 4);
    *(float4*)(&red[wv][e0 + 512]) = *(float4*)(acc1);
    *(float4*)(&red[wv][e0 + 516]) = *(float4*)(acc1 + 4);
    __syncthreads();

    const int o = t * 4;
    float4 r0 = *(float4*)(&red[0][o]);
    float4 r1 = *(float4*)(&red[1][o]);
    float4 r2 = *(float4*)(&red[2][o]);
    float4 r3 = *(float4*)(&red[3][o]);
    float4 r;
    r.x = (r0.x + r1.x) + (r2.x + r3.x);
    r.y = (r0.y + r1.y) + (r2.y + r3.y);
    r.z = (r0.z + r1.z) + (r2.z + r3.z);
    r.w = (r0.w + r1.w) + (r2.w + r3.w);
    *(float4*)(spart + ((size_t)b * 16 + jc) * CL + o) = r;
}

// ---------------------------------------------------------------------------
// Squash: sums the 16 per-jc partials, adds biases, squashes.
// Optionally emits vlog_out = v + vprev (cumulative logit v).
// ---------------------------------------------------------------------------
__global__ __launch_bounds__(256) void squash_kernel(const float* __restrict__ spart,
                                                     const float* __restrict__ biases,
                                                     float* __restrict__ vout,
                                                     float* __restrict__ vlog_out,
                                                     const float* __restrict__ vprev) {
    const int b = blockIdx.x;
    const int t = threadIdx.x;

    float4 sv = make_float4(0.f, 0.f, 0.f, 0.f);
#pragma unroll
    for (int p = 0; p < 16; ++p) {
        float4 q = *(const float4*)(spart + ((size_t)b * 16 + p) * CL + t * 4);
        sv.x += q.x; sv.y += q.y; sv.z += q.z; sv.w += q.w;
    }
    float4 bi = *(const float4*)(biases + t * 4);
    sv.x += bi.x; sv.y += bi.y; sv.z += bi.z; sv.w += bi.w;

    float n2 = sv.x * sv.x + sv.y * sv.y + sv.z * sv.z + sv.w * sv.w;
    n2 += __shfl_xor(n2, 1);
    n2 += __shfl_xor(n2, 2);
    n2 += __shfl_xor(n2, 4);

    float n = sqrtf(n2);
    float f = n2 / ((1.f + n2) * (n + 1e-7f));

    float4 v;
    v.x = f * sv.x; v.y = f * sv.y; v.z = f * sv.z; v.w = f * sv.w;
    *(float4*)(vout + b * CL + t * 4) = v;

    if (vlog_out != nullptr) {
        float4 a = make_float4(0.f, 0.f, 0.f, 0.f);
        if (vprev != nullptr) a = *(const float4*)(vprev + b * CL + t * 4);
        float4 o;
        o.x = v.x + a.x; o.y = v.y + a.y; o.z = v.z + a.z; o.w = v.w + a.w;
        *(float4*)(vlog_out + b * CL + t * 4) = o;
    }
}

// ---------------------------------------------------------------------------
extern "C" void kernel_launch(void* const* d_in, const int* in_sizes, int n_in,
                              void* d_out, int out_size, void* d_ws, size_t ws_size,
                              hipStream_t stream) {
    const float* x      = (const float*)d_in[0];   // (32, 2048, 32)
    const float* W      = (const float*)d_in[1];   // (2048, 32, 1024)
    const float* biases = (const float*)d_in[2];   // (32, 32)
    float* out = (float*)d_out;                    // (32, 32, 32)

    unsigned short* u = (unsigned short*)d_ws;                     // 128 MB bf16
    float* fb    = (float*)((char*)d_ws + (size_t)NB * NCAP * CL * 2);
    float* spart = fb;                  // 32*16*1024 floats
    float* v0    = spart + 524288;
    float* vl2   = v0 + 32768;
    float* vdmp  = vl2 + 32768;

    compute_u<<<NCAP * 2, 256, 0, stream>>>(x, W, u);

    dim3 rg(NB, 16);
    // r = 0: zero logits -> coupling exactly 1/32, no softmax needed
    route_pass<false><<<rg, 256, 0, stream>>>(u, nullptr, spart);
    squash_kernel<<<NB, 256, 0, stream>>>(spart, biases, v0, nullptr, nullptr);
    // r = 1: logits = u . v0
    route_pass<true><<<rg, 256, 0, stream>>>(u, v0, spart);
    squash_kernel<<<NB, 256, 0, stream>>>(spart, biases, vdmp, vl2, v0);
    // r = 2: logits = u . (v0 + v1)
    route_pass<true><<<rg, 256, 0, stream>>>(u, vl2, spart);
    squash_kernel<<<NB, 256, 0, stream>>>(spart, biases, out, nullptr, nullptr);
}